// Round 17
// baseline (146.876 us; speedup 1.0000x reference)
//
#include <hip/hip_runtime.h>
#include <hip/hip_fp16.h>
#include <stdint.h>

#define NB  32
#define NLQ 128
#define NLK 4096
#define NDK 256
#define NDV 256
#define KT  16
#define SPLITS 16
#define MINSPLITS 8
#define VST 18   // VT row stride (f16): even (4B-align) + odd/2 -> ~2-way banks

typedef _Float16 f16;
typedef _Float16 f16x2 __attribute__((ext_vector_type(2)));
typedef _Float16 f16x4 __attribute__((ext_vector_type(4)));
typedef _Float16 f16x8 __attribute__((ext_vector_type(8)));
typedef float    f32x4 __attribute__((ext_vector_type(4)));

// ---------------- Kernel 1: per (key-split s, batch b, q-half) partials -----
// 8 waves = (4 q-tiles x 2 dv-halves); wave = 16 queries x 128 dv.
// Occupancy rule consolidated over r3-r16: VGPR granule steps 64/128/256, so
// 8-wave blocks pair ONLY at arch <= 64 (r13: 60 -> 40.7%; r12: 76 -> 21.7%).
// This round: efficient-V AND arch<=64 together:
//   Q in LDS (kills 32-reg qf; r12-proven swizzle)
//   K in LDS (r9-proven KT=16 swizzle), ks[2]
//   V in LDS TRANSPOSED: VT[dv][k], stride 18 -> PV B-frag = 2 f16x2 reads
//     per MFMA (16 LDS-read instrs/wave/tile vs 64 u16). vs[2].
// Defer-max + normalized partials (r13). S=16 -> 1024 blocks.
__global__ __launch_bounds__(512) void fvta_part1(
    const float* __restrict__ q_, const float* __restrict__ k_,
    const float* __restrict__ v_, const int* __restrict__ mask_,
    f16* __restrict__ accw, float* __restrict__ mlw)
{
    __shared__ __align__(16) f16 QA[64 * NDK];      // 32 KB
    __shared__ __align__(16) f16 KA[2][KT * NDK];   // 16 KB
    __shared__ __align__(16) f16 VT[2][NDV * VST];  // 18 KB
    __shared__ int MK[NLK / MINSPLITS];             // 2 KB   (total 68 KB)

    const int tid = threadIdx.x, w = tid >> 6, lane = tid & 63;
    const int l15 = lane & 15, lhi = lane >> 4;
    const int qsub = w >> 1;          // 0..3: q-tile within block
    const int dvh  = w & 1;           // 0..1: dv half
    const int x = blockIdx.x, b = blockIdx.y;
    const int S = gridDim.x >> 1;
    const int s = x >> 1, qz = x & 1;
    const int slice = NLK / S, nt = slice / KT, kbase = s * slice;
    const float NEG = -__builtin_inff();

    const float* kb = k_ + ((size_t)b * NLK + kbase) * NDK;
    const float* vb = v_ + ((size_t)b * NLK + kbase) * NDV;
    const int*   mb = mask_ + b * NLK + kbase;

    for (int i = tid; i < slice; i += 512) MK[i] = mb[i];

    // ---- stage Q rows [qz*64, qz*64+64) f32->f16, XOR swizzle (r12-proven)
    {
        const float* qsrc = q_ + ((size_t)b * NLQ + qz * 64) * NDK;
        #pragma unroll
        for (int r = 0; r < 8; ++r) {
            const int idx = r * 512 + tid;        // 0..4095
            const int qq  = idx >> 6;             // row 0..63
            const int d   = (idx & 63) * 4;
            f32x4 xv = *(const f32x4*)(qsrc + qq * NDK + d);
            f16x4 hh; hh[0]=(f16)xv[0]; hh[1]=(f16)xv[1]; hh[2]=(f16)xv[2]; hh[3]=(f16)xv[3];
            *(f16x4*)(QA + qq * NDK + (d ^ ((qq & 15) << 3))) = hh;
        }
    }

    f32x4 accu[8];    // O[q=lhi*4+j][dv = dvh*128 + d*16 + l15]  (32 AGPR)
    #pragma unroll
    for (int i = 0; i < 8; ++i) accu[i] = (f32x4){0.f, 0.f, 0.f, 0.f};
    float m_run = NEG, l_run = 0.f;

    f32x4 ks[2], vs[2];   // next-tile staging (16x256 f32 each / 512 threads)

    // thread's coords for both K and V: idx=r*512+tid, kk=idx>>6, c=(idx&63)*4
    auto stage = [&](f16* KAb, f16* VTb) {
        #pragma unroll
        for (int r = 0; r < 2; ++r) {
            const int kk = ((r * 512 + tid) >> 6);      // 0..15
            const int c  = (tid & 63) * 4;              // col (dim or dv)
            // K: row-major swizzled (r9-proven)
            f32x4 xv = ks[r];
            f16x4 hh; hh[0]=(f16)xv[0]; hh[1]=(f16)xv[1]; hh[2]=(f16)xv[2]; hh[3]=(f16)xv[3];
            *(f16x4*)(KAb + kk * NDK + (c ^ (kk << 3))) = hh;
            // V: transposed VT[dv][k], 4 scalar u16 writes (8-way, bounded)
            f32x4 yv = vs[r];
            #pragma unroll
            for (int i = 0; i < 4; ++i)
                VTb[(c + i) * VST + kk] = (f16)yv[i];
        }
    };
    auto loadKV = [&](int t) {
        const float* ksrc = kb + (size_t)t * KT * NDK;
        const float* vsrc = vb + (size_t)t * KT * NDV;
        #pragma unroll
        for (int r = 0; r < 2; ++r) {
            ks[r] = *(const f32x4*)(ksrc + (r * 512 + tid) * 4);
            vs[r] = *(const f32x4*)(vsrc + (r * 512 + tid) * 4);
        }
    };

    loadKV(0);
    stage(KA[0], VT[0]);
    __syncthreads();

    const int swz = l15 << 3;   // row&15 == l15 for Q and K reads

    for (int t = 0; t < nt; ++t) {
        const int cur = t & 1;
        if (t + 1 < nt) loadKV(t + 1);   // in flight through compute
        const int k0 = t * KT;

        // ---- QK^T over 16 keys (A = K rows, B = Q rows, both LDS)
        f32x4 s4 = (f32x4){0.f,0.f,0.f,0.f};
        {
            const f16* kp = &KA[cur][l15 * NDK];
            const f16* qp = &QA[(qsub * 16 + l15) * NDK];
            #pragma unroll
            for (int kd = 0; kd < 8; ++kd) {
                const int col = (kd * 32 + lhi * 8) ^ swz;
                f16x8 kf = *(const f16x8*)(kp + col);
                f16x8 qv = *(const f16x8*)(qp + col);
                s4 = __builtin_amdgcn_mfma_f32_16x16x32_f16(kf, qv, s4, 0, 0, 0);
            }
        }
        // s4[j] = S[key=k0+4lhi+j][q=l15]

        // ---- mask -> -inf, online softmax over 16 keys, defer-max
        const int4 m4 = *(const int4*)(MK + k0 + lhi * 4);
        float sa[4];
        sa[0] = m4.x ? NEG : s4[0]; sa[1] = m4.y ? NEG : s4[1];
        sa[2] = m4.z ? NEG : s4[2]; sa[3] = m4.w ? NEG : s4[3];

        float tmax = fmaxf(fmaxf(sa[0], sa[1]), fmaxf(sa[2], sa[3]));
        tmax = fmaxf(tmax, __shfl_xor(tmax, 16, 64));
        tmax = fmaxf(tmax, __shfl_xor(tmax, 32, 64));

        const bool defer = (m_run != NEG) && __all(tmax - m_run <= 8.f);
        if (!defer) {
            const float mnew = fmaxf(m_run, tmax);
            if (mnew != NEG) {
                const float scale = (m_run == NEG) ? 0.f : __expf(m_run - mnew);
                float scj[4];
                #pragma unroll
                for (int j = 0; j < 4; ++j) scj[j] = __shfl(scale, lhi * 4 + j, 64);
                #pragma unroll
                for (int d = 0; d < 8; ++d) {
                    accu[d][0] *= scj[0]; accu[d][1] *= scj[1];
                    accu[d][2] *= scj[2]; accu[d][3] *= scj[3];
                }
                l_run *= scale;
                m_run = mnew;
            }
        }

        float p4[4];
        if (m_run == NEG) {
            #pragma unroll
            for (int j = 0; j < 4; ++j) p4[j] = 0.f;
        } else {
            #pragma unroll
            for (int j = 0; j < 4; ++j) p4[j] = __expf(sa[j] - m_run);
        }
        float ps = (p4[0] + p4[1]) + (p4[2] + p4[3]);
        ps += __shfl_xor(ps, 16, 64);
        ps += __shfl_xor(ps, 32, 64);
        l_run += ps;

        f16x4 pa;
        pa[0]=(f16)p4[0]; pa[1]=(f16)p4[1]; pa[2]=(f16)p4[2]; pa[3]=(f16)p4[3];

        // ---- PV: B frag = V[k=4lhi+j][dv] = VT[dv][4lhi+j] -> 2 f16x2 reads
        {
            const f16* VTc = &VT[cur][0];
            #pragma unroll
            for (int d = 0; d < 8; ++d) {
                const int dv = dvh * 128 + d * 16 + l15;
                const f16* vp = VTc + dv * VST + 4 * lhi;
                f16x2 v0 = *(const f16x2*)(vp);
                f16x2 v1 = *(const f16x2*)(vp + 2);
                f16x4 vf; vf[0]=v0[0]; vf[1]=v0[1]; vf[2]=v1[0]; vf[3]=v1[1];
                accu[d] = __builtin_amdgcn_mfma_f32_16x16x16f16(
                    pa, vf, accu[d], 0, 0, 0);
            }
        }

        if (t + 1 < nt) stage(KA[cur ^ 1], VT[cur ^ 1]);
        __syncthreads();
    }

    // ---- write NORMALIZED partials accu/l (f16-safe under defer-max)
    const float rl = (l_run > 0.f) ? 1.f / l_run : 0.f;
    float rlj[4];
    #pragma unroll
    for (int j = 0; j < 4; ++j) rlj[j] = __shfl(rl, lhi * 4 + j, 64);

    const size_t base = (size_t)(b * S + s) * NLQ + qz * 64 + qsub * 16;
    #pragma unroll
    for (int j = 0; j < 4; ++j) {
        f16* dst = accw + (base + lhi * 4 + j) * NDV + dvh * 128 + l15;
        #pragma unroll
        for (int d = 0; d < 8; ++d) dst[d * 16] = (f16)(accu[d][j] * rlj[j]);
    }
    if (dvh == 0 && lane < 16) {
        mlw[(base + lane) * 2]     = m_run;
        mlw[(base + lane) * 2 + 1] = l_run;
    }
}

// ---------------- Kernel 2: merge key-splits, q-length mask, mean ----------
// Partials normalized: O = sum_ss accw_ss * (l_ss * exp(m_ss-gm) / L).
__global__ __launch_bounds__(256) void fvta_merge(
    const f16* __restrict__ accw, const float* __restrict__ mlw,
    const int* __restrict__ qlen_, float* __restrict__ out_, int S)
{
    __shared__ float fac[8][SPLITS + 1];
    const int qc = blockIdx.x, b = blockIdx.y, tid = threadIdx.x;
    const int len = qlen_[b];
    const float NEG = -__builtin_inff();

    if (tid < 8) {
        const int q = qc * 8 + tid;
        if (q < len) {
            float gm = NEG;
            for (int ss = 0; ss < S; ++ss)
                gm = fmaxf(gm, mlw[((size_t)(b * S + ss) * NLQ + q) * 2]);
            float L = 0.f;
            for (int ss = 0; ss < S; ++ss) {
                const float m = mlw[((size_t)(b * S + ss) * NLQ + q) * 2];
                const float l = mlw[((size_t)(b * S + ss) * NLQ + q) * 2 + 1];
                if (m != NEG) L += l * __expf(m - gm);
            }
            for (int ss = 0; ss < S; ++ss) {
                const float m = mlw[((size_t)(b * S + ss) * NLQ + q) * 2];
                const float l = mlw[((size_t)(b * S + ss) * NLQ + q) * 2 + 1];
                fac[tid][ss] = (gm != NEG && L > 0.f && m != NEG)
                             ? l * __expf(m - gm) / L : 0.f;
            }
        } else {
            for (int ss = 0; ss < S; ++ss) fac[tid][ss] = 0.f;
        }
    }
    __syncthreads();

    float sum = 0.f;
    for (int qq = 0; qq < 8; ++qq) {
        const int q = qc * 8 + qq;
        for (int ss = 0; ss < S; ++ss) {
            const float f = fac[qq][ss];
            if (f != 0.f)
                sum += (float)accw[((size_t)(b * S + ss) * NLQ + q) * NDV + tid] * f;
        }
    }
    atomicAdd(&out_[b * NDV + tid], sum * (1.f / NLQ));
}

extern "C" void kernel_launch(void* const* d_in, const int* in_sizes, int n_in,
                              void* d_out, int out_size, void* d_ws, size_t ws_size,
                              hipStream_t stream) {
    const float* q    = (const float*)d_in[0];
    const int*   qlen = (const int*)d_in[1];
    const float* k    = (const float*)d_in[2];
    const float* v    = (const float*)d_in[3];
    const int*   mask = (const int*)d_in[4];
    float* out = (float*)d_out;

    int S = SPLITS;   // auto-halve if ws is small (MK sized for S>=MINSPLITS)
    while (S > MINSPLITS &&
           ((size_t)NB * S * NLQ * NDV * 2 + (size_t)NB * S * NLQ * 8) > ws_size)
        S >>= 1;
    f16*   accw = (f16*)d_ws;
    float* mlw  = (float*)((char*)d_ws + (size_t)NB * S * NLQ * NDV * 2);

    hipMemsetAsync(out, 0, (size_t)out_size * sizeof(float), stream);
    dim3 g1(2 * S, NB);   // x = (s, qz): qz-pairs adjacent in dispatch order
    fvta_part1<<<g1, 512, 0, stream>>>(q, k, v, mask, accw, mlw);
    dim3 g2(NLQ / 8, NB);
    fvta_merge<<<g2, 256, 0, stream>>>(accw, mlw, qlen, out, S);
}